// Round 8
// baseline (420.150 us; speedup 1.0000x reference)
//
#include <hip/hip_runtime.h>
#include <hip/hip_bf16.h>
#include <math.h>

// Problem constants
#define B_     32
#define DM_    4096
#define H_     32
#define HKV_   8
#define G_     4
#define HD_    128
#define KVLEN_ 2048
#define NBPS_  8
#define NQKV_  6144   // 4096 q + 1024 k + 1024 v
#define QKSPLIT_ 32   // qkv split-K  (grid 24*32=768 = 3/CU exact)
#define QKC_     128  // 4096 / 32
#define OKSPLIT_ 16   // oproj split-K (grid 16*16=256 = 1/CU exact)
#define OKC_     256  // 4096 / 16
#define ASPLIT_ 16
#define APOS_  128    // positions per attention block
#define AREPS_ 3      // MEASUREMENT: run attention body 3x (reps 1,2 -> scratch)
#define PACC_STRIDE_ 2097152   // floats per pacc rep copy (16*32*32*128)
#define PLS_STRIDE_  16384     // floats per pls rep copy  (16*32*32)

typedef float vf4 __attribute__((ext_vector_type(4)));
typedef float vf2 __attribute__((ext_vector_type(2)));

// ---------------------------------------------------------------------------
// Kernel 0: transpose [32][4096] -> [4096][32]. grid = 64 blocks, 256 thr.
// ---------------------------------------------------------------------------
__global__ __launch_bounds__(256) void transpose32(
    const float* __restrict__ in, float* __restrict__ out) {
  __shared__ float t[32][65];
  const int tid = threadIdx.x;
  const int k0 = blockIdx.x * 64;
  #pragma unroll
  for (int it = 0; it < 8; ++it) {
    int m = it * 4 + (tid >> 6);
    int k = tid & 63;
    t[m][k] = in[(size_t)m * DM_ + k0 + k];
  }
  __syncthreads();
  #pragma unroll
  for (int it = 0; it < 8; ++it) {
    int flat = it * 256 + tid;
    out[(size_t)k0 * 32 + flat] = t[flat & 31][flat >> 5];
  }
}

// ---------------------------------------------------------------------------
// Kernel 1: fused QKV projection, split-K partials, NO LDS (R4 template).
// grid = 24 n-tiles * 32 k-splits = 768 blocks (3/CU), 256 threads.
// ---------------------------------------------------------------------------
__global__ __launch_bounds__(256) void qkv_gemm(
    const float* __restrict__ seqsT, const float* __restrict__ Wq,
    const float* __restrict__ Wk, const float* __restrict__ Wv,
    float* __restrict__ P1) {
  const int tid = threadIdx.x;
  const int nid = blockIdx.x % 24;
  const int kid = blockIdx.x / 24;
  const int k0 = kid * QKC_;

  const int ct = tid & 127;
  const int mh16 = __builtin_amdgcn_readfirstlane((tid >> 7) << 4);  // 0 or 16
  const int n  = nid * 256 + ct * 2;

  const float* W; int col, ldw;
  if (nid < 16)      { W = Wq; col = n;        ldw = 4096; }
  else if (nid < 20) { W = Wk; col = n - 4096; ldw = 1024; }
  else               { W = Wv; col = n - 5120; ldw = 1024; }

  float2 acc[16];
  #pragma unroll
  for (int r = 0; r < 16; ++r) acc[r] = make_float2(0.f, 0.f);

  const vf2* wp = (const vf2*)(W + (size_t)k0 * ldw + col);
  const int ldw2 = ldw >> 1;
  const vf4* ap = (const vf4*)(seqsT + (size_t)k0 * 32 + mh16);

  #pragma unroll 8
  for (int kk = 0; kk < QKC_; ++kk) {
    vf2 w = __builtin_nontemporal_load(wp + (size_t)kk * ldw2);
    vf4 a0 = ap[kk * 8 + 0];
    vf4 a1 = ap[kk * 8 + 1];
    vf4 a2 = ap[kk * 8 + 2];
    vf4 a3 = ap[kk * 8 + 3];
    #define FMA2(av, r) \
      acc[r].x = fmaf(av, w.x, acc[r].x); acc[r].y = fmaf(av, w.y, acc[r].y);
    FMA2(a0.x, 0)  FMA2(a0.y, 1)  FMA2(a0.z, 2)  FMA2(a0.w, 3)
    FMA2(a1.x, 4)  FMA2(a1.y, 5)  FMA2(a1.z, 6)  FMA2(a1.w, 7)
    FMA2(a2.x, 8)  FMA2(a2.y, 9)  FMA2(a2.z, 10) FMA2(a2.w, 11)
    FMA2(a3.x, 12) FMA2(a3.y, 13) FMA2(a3.z, 14) FMA2(a3.w, 15)
    #undef FMA2
  }

  float* o = P1 + (size_t)kid * 32 * NQKV_ + n;
  #pragma unroll
  for (int r = 0; r < 16; ++r) {
    int m = mh16 + r;
    *(float2*)(o + (size_t)m * NQKV_) = acc[r];
  }
}

// ---------------------------------------------------------------------------
// Kernel 2: reduce split-K partials, RMSNorm (q,k), RoPE (q,k).
// ---------------------------------------------------------------------------
__global__ __launch_bounds__(128) void reduce_norm_rope(
    const float* __restrict__ P1, const float* __restrict__ qn_w,
    const float* __restrict__ kn_w, const int* __restrict__ input_pos,
    float* __restrict__ qf, float* __restrict__ knew, float* __restrict__ vnew) {
  const int b = blockIdx.x / 48;
  const int hh = blockIdx.x % 48;
  const int tid = threadIdx.x;

  int col0, kind;  // 0=q,1=k,2=v
  if (hh < 32)      { kind = 0; col0 = hh * 128; }
  else if (hh < 40) { kind = 1; col0 = 4096 + (hh - 32) * 128; }
  else              { kind = 2; col0 = 5120 + (hh - 40) * 128; }

  float x = 0.f;
  const float* p = P1 + (size_t)b * NQKV_ + col0 + tid;
  #pragma unroll
  for (int s = 0; s < QKSPLIT_; ++s) x += p[(size_t)s * 32 * NQKV_];

  if (kind == 2) {
    vnew[(size_t)b * 1024 + (hh - 40) * 128 + tid] = x;
    return;
  }

  __shared__ float lds[128];
  __shared__ float wred[2];
  float ss = x * x;
  #pragma unroll
  for (int off = 32; off > 0; off >>= 1) ss += __shfl_down(ss, off);
  if ((tid & 63) == 0) wred[tid >> 6] = ss;
  __syncthreads();
  float tot = wred[0] + wred[1];
  float r = rsqrtf(tot * (1.f / 128.f) + 1e-6f);
  const float* wv = (kind == 0) ? qn_w : kn_w;
  x = x * r * wv[tid];

  lds[tid] = x;
  __syncthreads();

  if (tid < 64) {
    float pos = (float)input_pos[b];
    float inv = exp2f(-(float)tid * 0.20762050593045952f);
    float ang = pos * inv;
    float c = cosf(ang), s = sinf(ang);
    float x1 = lds[tid], x2 = lds[tid + 64];
    float o1 = x1 * c - x2 * s;
    float o2 = x2 * c + x1 * s;
    float* dst = (kind == 0) ? (qf + (size_t)b * 4096 + hh * 128)
                             : (knew + (size_t)b * 1024 + (hh - 32) * 128);
    dst[tid] = o1;
    dst[tid + 64] = o2;
  }
}

// ---------------------------------------------------------------------------
// Kernel 3: paged GQA decode attention — MEASUREMENT build: body runs
// AREPS_ times; rep r writes to pacc + r*stride (distinct, not dead);
// merge consumes rep 0. Body identical to R7.
// ---------------------------------------------------------------------------
__global__ __launch_bounds__(512, 4) void attn_decode(
    const float* __restrict__ qf, const float* __restrict__ knew,
    const float* __restrict__ vnew, const float* __restrict__ kc,
    const float* __restrict__ vc, const int* __restrict__ block_tables,
    const int* __restrict__ slot_mapping, const int* __restrict__ context_lens,
    float* __restrict__ pacc, float* __restrict__ pls) {
  const int b   = blockIdx.x >> 4;
  const int sp  = blockIdx.x & 15;
  const int tid = threadIdx.x;
  const int w   = tid >> 6;        // kv head 0..7
  const int lane = tid & 63;
  const int gi  = lane >> 4;       // position-in-quad 0..3
  const int l16 = lane & 15;
  const int d0  = l16 * 8;

  const int ctx   = context_lens[b];
  const int fslot = slot_mapping[b];
  const int base  = sp * APOS_;

  const int page  = block_tables[b * NBPS_ + (base >> 8)];
  const int slot0 = (page << 8) + (base & 255);
  const int rel   = fslot - slot0;
  const bool hasf = (rel >= 0) && (rel < APOS_);
  const int nv    = min(APOS_, ctx - base);

  const float scale = 0.08838834764831845f;  // 1/sqrt(128)
  float q[4][8];
  #pragma unroll
  for (int g = 0; g < 4; ++g) {
    const float4* qp = (const float4*)(qf + ((size_t)b * H_ + w * G_ + g) * HD_ + d0);
    float4 a = qp[0], c = qp[1];
    q[g][0] = a.x * scale; q[g][1] = a.y * scale; q[g][2] = a.z * scale; q[g][3] = a.w * scale;
    q[g][4] = c.x * scale; q[g][5] = c.y * scale; q[g][6] = c.z * scale; q[g][7] = c.w * scale;
  }

  const float* knp = knew + ((size_t)b * HKV_ + w) * HD_ + d0;
  const float* vnp = vnew + ((size_t)b * HKV_ + w) * HD_ + d0;
  const float* kcb = kc + ((size_t)slot0 * HKV_ + w) * HD_ + d0;
  const float* vcb = vc + ((size_t)slot0 * HKV_ + w) * HD_ + d0;

  #define ATTN_STEP(K1, K2, V1, V2, SGN)                                  \
    {                                                                     \
      float kk8[8] = {K1.x, K1.y, K1.z, K1.w, K2.x, K2.y, K2.z, K2.w};    \
      float vv[8]  = {V1.x, V1.y, V1.z, V1.w, V2.x, V2.y, V2.z, V2.w};    \
      float s[4];                                                         \
      _Pragma("unroll")                                                   \
      for (int g = 0; g < 4; ++g) {                                       \
        float t = 0.f;                                                    \
        _Pragma("unroll")                                                 \
        for (int j = 0; j < 8; ++j) t = fmaf(q[g][j], kk8[j], t);         \
        s[g] = t;                                                         \
      }                                                                   \
      _Pragma("unroll")                                                   \
      for (int o2 = 1; o2 < 16; o2 <<= 1) {                               \
        _Pragma("unroll")                                                 \
        for (int g = 0; g < 4; ++g) s[g] += __shfl_xor(s[g], o2);         \
      }                                                                   \
      _Pragma("unroll")                                                   \
      for (int g = 0; g < 4; ++g) {                                       \
        float pw = (SGN) * __expf(s[g]);                                  \
        ls[g] += pw;                                                      \
        _Pragma("unroll")                                                 \
        for (int j = 0; j < 8; ++j) acc[g][j] = fmaf(pw, vv[j], acc[g][j]); \
      }                                                                   \
    }

  for (int rep = 0; rep < AREPS_; ++rep) {
    float ls[4] = {0.f, 0.f, 0.f, 0.f};
    float acc[4][8];
    #pragma unroll
    for (int g = 0; g < 4; ++g)
      #pragma unroll
      for (int j = 0; j < 8; ++j) acc[g][j] = 0.f;

    if (nv == APOS_) {
      #pragma unroll 2
      for (int it = 0; it < APOS_ / 4; ++it) {
        const int off = it * 4 + gi;
        const vf4* kp4 = (const vf4*)(kcb + (size_t)off * (HKV_ * HD_));
        const vf4* vp4 = (const vf4*)(vcb + (size_t)off * (HKV_ * HD_));
        vf4 k1 = __builtin_nontemporal_load(kp4);
        vf4 k2 = __builtin_nontemporal_load(kp4 + 1);
        vf4 v1 = __builtin_nontemporal_load(vp4);
        vf4 v2 = __builtin_nontemporal_load(vp4 + 1);
        ATTN_STEP(k1, k2, v1, v2, 1.f)
      }
      if (hasf && gi == (rel & 3)) {
        const float* kps = kcb + (size_t)rel * (HKV_ * HD_);
        const float* vps = vcb + (size_t)rel * (HKV_ * HD_);
        float4 k1 = ((const float4*)kps)[0];
        float4 k2 = ((const float4*)kps)[1];
        float4 v1 = ((const float4*)vps)[0];
        float4 v2 = ((const float4*)vps)[1];
        ATTN_STEP(k1, k2, v1, v2, -1.f)   // subtract stale
        float4 f1 = ((const float4*)knp)[0];
        float4 f2 = ((const float4*)knp)[1];
        float4 g1 = ((const float4*)vnp)[0];
        float4 g2 = ((const float4*)vnp)[1];
        ATTN_STEP(f1, f2, g1, g2, 1.f)    // add fresh
      }
    } else {
      for (int it = 0; it < APOS_ / 4; ++it) {
        const int off = it * 4 + gi;
        if (base + off < ctx) {
          const float* kp = (off == rel) ? knp : (kcb + (size_t)off * (HKV_ * HD_));
          const float* vp = (off == rel) ? vnp : (vcb + (size_t)off * (HKV_ * HD_));
          float4 k1 = ((const float4*)kp)[0];
          float4 k2 = ((const float4*)kp)[1];
          float4 v1 = ((const float4*)vp)[0];
          float4 v2 = ((const float4*)vp)[1];
          ATTN_STEP(k1, k2, v1, v2, 1.f)
        }
      }
    }

    // sum the 4 position-groups within the wave
    #pragma unroll
    for (int o2 = 16; o2 < 64; o2 <<= 1) {
      #pragma unroll
      for (int g = 0; g < 4; ++g) {
        ls[g] += __shfl_xor(ls[g], o2);
        #pragma unroll
        for (int j = 0; j < 8; ++j) acc[g][j] += __shfl_xor(acc[g][j], o2);
      }
    }

    if (gi == 0) {
      float* pacc_r = pacc + (size_t)rep * PACC_STRIDE_;
      float* pls_r  = pls  + (size_t)rep * PLS_STRIDE_;
      #pragma unroll
      for (int g = 0; g < 4; ++g) {
        float* dst = pacc_r + (((size_t)sp * B_ + b) * H_ + (w * G_ + g)) * HD_ + d0;
        float4 o1 = {acc[g][0], acc[g][1], acc[g][2], acc[g][3]};
        float4 o2 = {acc[g][4], acc[g][5], acc[g][6], acc[g][7]};
        ((float4*)dst)[0] = o1;
        ((float4*)dst)[1] = o2;
        if (l16 == 0) pls_r[((size_t)sp * B_ + b) * H_ + (w * G_ + g)] = ls[g];
      }
    }
  }
  #undef ATTN_STEP
}

// ---------------------------------------------------------------------------
// Kernel 3b: merge KV-split partials (rep 0) -> attnT[k][b]. grid = 128x256.
// ---------------------------------------------------------------------------
__global__ __launch_bounds__(256) void attn_mergeT(
    const float* __restrict__ pacc, const float* __restrict__ pls,
    float* __restrict__ attnT) {
  const int idx = blockIdx.x * 256 + threadIdx.x;  // float4 index, < 32768
  const int b   = idx >> 10;
  const int h   = (idx >> 5) & 31;
  const int d4  = (idx & 31) * 4;
  const int bh  = idx >> 5;                        // b*32 + h
  const float4* p4 = (const float4*)pacc;
  float4 A = {0.f, 0.f, 0.f, 0.f};
  float L = 0.f;
  #pragma unroll
  for (int sp = 0; sp < ASPLIT_; ++sp) {
    float4 t = p4[(size_t)sp * 32768 + idx];
    A.x += t.x; A.y += t.y; A.z += t.z; A.w += t.w;
    L += pls[sp * (B_ * H_) + bh];
  }
  float r = 1.f / L;
  float* dst = attnT + ((size_t)(h * 128 + d4)) * 32 + b;
  dst[0]  = A.x * r;
  dst[32] = A.y * r;
  dst[64] = A.z * r;
  dst[96] = A.w * r;
}

// ---------------------------------------------------------------------------
// Kernel 4: output projection, split-K partials, NO LDS (R4 template).
// ---------------------------------------------------------------------------
__global__ __launch_bounds__(512) void oproj_gemm(
    const float* __restrict__ attnT, const float* __restrict__ Wo,
    float* __restrict__ P2) {
  const int tid = threadIdx.x;
  const int nid = blockIdx.x & 15;
  const int kid = blockIdx.x >> 4;
  const int k0 = kid * OKC_;

  const int ct = tid & 127;
  const int mq8 = __builtin_amdgcn_readfirstlane((tid >> 7) << 3);  // 0,8,16,24
  const int n  = nid * 256 + ct * 2;

  float2 acc[8];
  #pragma unroll
  for (int r = 0; r < 8; ++r) acc[r] = make_float2(0.f, 0.f);

  const vf2* wp = (const vf2*)(Wo + (size_t)k0 * 4096 + n);
  const vf4* ap = (const vf4*)(attnT + (size_t)k0 * 32 + mq8);

  #pragma unroll 8
  for (int kk = 0; kk < OKC_; ++kk) {
    vf2 w = __builtin_nontemporal_load(wp + (size_t)kk * 2048);
    vf4 a0 = ap[kk * 8 + 0];
    vf4 a1 = ap[kk * 8 + 1];
    #define FMA2(av, r) \
      acc[r].x = fmaf(av, w.x, acc[r].x); acc[r].y = fmaf(av, w.y, acc[r].y);
    FMA2(a0.x, 0) FMA2(a0.y, 1) FMA2(a0.z, 2) FMA2(a0.w, 3)
    FMA2(a1.x, 4) FMA2(a1.y, 5) FMA2(a1.z, 6) FMA2(a1.w, 7)
    #undef FMA2
  }

  float* o = P2 + (size_t)kid * 32 * 4096 + n;
  #pragma unroll
  for (int r = 0; r < 8; ++r) {
    int m = mq8 + r;
    *(float2*)(o + (size_t)m * 4096) = acc[r];
  }
}

// ---------------------------------------------------------------------------
// Kernel 5: reduce split-K partials of the output projection -> d_out.
// ---------------------------------------------------------------------------
__global__ __launch_bounds__(256) void oproj_reduce(
    const float* __restrict__ P2, float* __restrict__ out) {
  const int idx = blockIdx.x * 256 + threadIdx.x;  // float4 index
  const float4* p4 = (const float4*)P2;
  float4 s = {0.f, 0.f, 0.f, 0.f};
  #pragma unroll
  for (int t = 0; t < OKSPLIT_; ++t) {
    float4 v = p4[(size_t)t * 32768 + idx];
    s.x += v.x; s.y += v.y; s.z += v.z; s.w += v.w;
  }
  ((float4*)out)[idx] = s;
}

// ---------------------------------------------------------------------------
extern "C" void kernel_launch(void* const* d_in, const int* in_sizes, int n_in,
                              void* d_out, int out_size, void* d_ws, size_t ws_size,
                              hipStream_t stream) {
  const float* seqs = (const float*)d_in[0];
  const float* Wq   = (const float*)d_in[1];
  const float* Wk   = (const float*)d_in[2];
  const float* Wv   = (const float*)d_in[3];
  const float* Wo   = (const float*)d_in[4];
  const float* qn_w = (const float*)d_in[5];
  const float* kn_w = (const float*)d_in[6];
  const float* kc   = (const float*)d_in[7];
  const float* vc   = (const float*)d_in[8];
  const int* input_pos = (const int*)d_in[9];
  const int* slot_map  = (const int*)d_in[10];
  const int* btab      = (const int*)d_in[11];
  const int* ctx       = (const int*)d_in[12];
  float* out = (float*)d_out;

  char* w = (char*)d_ws;
  float* seqsT = (float*)(w);                    //      524,288
  float* P1    = (float*)(w + 524288);           //   25,165,824 (32 splits)
  float* qf    = (float*)(w + 25690112);         //      524,288
  float* knew  = (float*)(w + 26214400);         //      131,072
  float* vnew  = (float*)(w + 26345472);         //      131,072
  float* attnT = (float*)(w + 26476544);         //      524,288
  float* pacc  = (float*)(w + 27000832);         //   25,165,824 (3 reps)
  float* pls   = (float*)(w + 52166656);         //      196,608 (3 reps)
  float* P2    = (float*)(w + 52363264);         //   16,777,216 (16 splits)

  transpose32<<<64, 256, 0, stream>>>(seqs, seqsT);
  qkv_gemm<<<24 * QKSPLIT_, 256, 0, stream>>>(seqsT, Wq, Wk, Wv, P1);
  reduce_norm_rope<<<B_ * 48, 128, 0, stream>>>(P1, qn_w, kn_w, input_pos, qf, knew, vnew);
  attn_decode<<<B_ * ASPLIT_, 512, 0, stream>>>(qf, knew, vnew, kc, vc, btab, slot_map, ctx, pacc, pls);
  attn_mergeT<<<128, 256, 0, stream>>>(pacc, pls, attnT);
  oproj_gemm<<<16 * OKSPLIT_, 512, 0, stream>>>(attnT, Wo, P2);
  oproj_reduce<<<128, 256, 0, stream>>>(P2, out);
}

// Round 9
// 401.406 us; speedup vs baseline: 1.0467x; 1.0467x over previous
//
#include <hip/hip_runtime.h>
#include <hip/hip_bf16.h>
#include <math.h>

// Problem constants
#define B_     32
#define DM_    4096
#define H_     32
#define HKV_   8
#define G_     4
#define HD_    128
#define KVLEN_ 2048
#define NBPS_  8
#define NQKV_  6144   // 4096 q + 1024 k + 1024 v
#define QKSPLIT_ 32   // qkv split-K  (grid 24*32=768 = 3/CU exact)
#define QKC_     128  // 4096 / 32
#define OKSPLIT_ 16   // oproj split-K (grid 16*16=256 = 1/CU exact)
#define OKC_     256  // 4096 / 16
#define ASPLIT_ 32    // attention KV-split: 32*32=1024 blocks = 4/CU exact
#define APOS_  64     // positions per attention block (KVLEN/ASPLIT)

typedef float vf4 __attribute__((ext_vector_type(4)));
typedef float vf2 __attribute__((ext_vector_type(2)));

// ---------------------------------------------------------------------------
// Kernel 0: transpose [32][4096] -> [4096][32]. grid = 64 blocks, 256 thr.
// ---------------------------------------------------------------------------
__global__ __launch_bounds__(256) void transpose32(
    const float* __restrict__ in, float* __restrict__ out) {
  __shared__ float t[32][65];
  const int tid = threadIdx.x;
  const int k0 = blockIdx.x * 64;
  #pragma unroll
  for (int it = 0; it < 8; ++it) {
    int m = it * 4 + (tid >> 6);
    int k = tid & 63;
    t[m][k] = in[(size_t)m * DM_ + k0 + k];
  }
  __syncthreads();
  #pragma unroll
  for (int it = 0; it < 8; ++it) {
    int flat = it * 256 + tid;
    out[(size_t)k0 * 32 + flat] = t[flat & 31][flat >> 5];
  }
}

// ---------------------------------------------------------------------------
// Kernel 1: fused QKV projection, split-K partials, NO LDS (R4 template).
// grid = 24 n-tiles * 32 k-splits = 768 blocks (3/CU), 256 threads.
// ---------------------------------------------------------------------------
__global__ __launch_bounds__(256) void qkv_gemm(
    const float* __restrict__ seqsT, const float* __restrict__ Wq,
    const float* __restrict__ Wk, const float* __restrict__ Wv,
    float* __restrict__ P1) {
  const int tid = threadIdx.x;
  const int nid = blockIdx.x % 24;
  const int kid = blockIdx.x / 24;
  const int k0 = kid * QKC_;

  const int ct = tid & 127;
  const int mh16 = __builtin_amdgcn_readfirstlane((tid >> 7) << 4);  // 0 or 16
  const int n  = nid * 256 + ct * 2;

  const float* W; int col, ldw;
  if (nid < 16)      { W = Wq; col = n;        ldw = 4096; }
  else if (nid < 20) { W = Wk; col = n - 4096; ldw = 1024; }
  else               { W = Wv; col = n - 5120; ldw = 1024; }

  float2 acc[16];
  #pragma unroll
  for (int r = 0; r < 16; ++r) acc[r] = make_float2(0.f, 0.f);

  const vf2* wp = (const vf2*)(W + (size_t)k0 * ldw + col);
  const int ldw2 = ldw >> 1;
  const vf4* ap = (const vf4*)(seqsT + (size_t)k0 * 32 + mh16);

  #pragma unroll 8
  for (int kk = 0; kk < QKC_; ++kk) {
    vf2 w = __builtin_nontemporal_load(wp + (size_t)kk * ldw2);
    vf4 a0 = ap[kk * 8 + 0];
    vf4 a1 = ap[kk * 8 + 1];
    vf4 a2 = ap[kk * 8 + 2];
    vf4 a3 = ap[kk * 8 + 3];
    #define FMA2(av, r) \
      acc[r].x = fmaf(av, w.x, acc[r].x); acc[r].y = fmaf(av, w.y, acc[r].y);
    FMA2(a0.x, 0)  FMA2(a0.y, 1)  FMA2(a0.z, 2)  FMA2(a0.w, 3)
    FMA2(a1.x, 4)  FMA2(a1.y, 5)  FMA2(a1.z, 6)  FMA2(a1.w, 7)
    FMA2(a2.x, 8)  FMA2(a2.y, 9)  FMA2(a2.z, 10) FMA2(a2.w, 11)
    FMA2(a3.x, 12) FMA2(a3.y, 13) FMA2(a3.z, 14) FMA2(a3.w, 15)
    #undef FMA2
  }

  float* o = P1 + (size_t)kid * 32 * NQKV_ + n;
  #pragma unroll
  for (int r = 0; r < 16; ++r) {
    int m = mh16 + r;
    *(float2*)(o + (size_t)m * NQKV_) = acc[r];
  }
}

// ---------------------------------------------------------------------------
// Kernel 2: reduce split-K partials, RMSNorm (q,k), RoPE (q,k).
// ---------------------------------------------------------------------------
__global__ __launch_bounds__(128) void reduce_norm_rope(
    const float* __restrict__ P1, const float* __restrict__ qn_w,
    const float* __restrict__ kn_w, const int* __restrict__ input_pos,
    float* __restrict__ qf, float* __restrict__ knew, float* __restrict__ vnew) {
  const int b = blockIdx.x / 48;
  const int hh = blockIdx.x % 48;
  const int tid = threadIdx.x;

  int col0, kind;  // 0=q,1=k,2=v
  if (hh < 32)      { kind = 0; col0 = hh * 128; }
  else if (hh < 40) { kind = 1; col0 = 4096 + (hh - 32) * 128; }
  else              { kind = 2; col0 = 5120 + (hh - 40) * 128; }

  float x = 0.f;
  const float* p = P1 + (size_t)b * NQKV_ + col0 + tid;
  #pragma unroll
  for (int s = 0; s < QKSPLIT_; ++s) x += p[(size_t)s * 32 * NQKV_];

  if (kind == 2) {
    vnew[(size_t)b * 1024 + (hh - 40) * 128 + tid] = x;
    return;
  }

  __shared__ float lds[128];
  __shared__ float wred[2];
  float ss = x * x;
  #pragma unroll
  for (int off = 32; off > 0; off >>= 1) ss += __shfl_down(ss, off);
  if ((tid & 63) == 0) wred[tid >> 6] = ss;
  __syncthreads();
  float tot = wred[0] + wred[1];
  float r = rsqrtf(tot * (1.f / 128.f) + 1e-6f);
  const float* wv = (kind == 0) ? qn_w : kn_w;
  x = x * r * wv[tid];

  lds[tid] = x;
  __syncthreads();

  if (tid < 64) {
    float pos = (float)input_pos[b];
    float inv = exp2f(-(float)tid * 0.20762050593045952f);
    float ang = pos * inv;
    float c = cosf(ang), s = sinf(ang);
    float x1 = lds[tid], x2 = lds[tid + 64];
    float o1 = x1 * c - x2 * s;
    float o2 = x2 * c + x1 * s;
    float* dst = (kind == 0) ? (qf + (size_t)b * 4096 + hh * 128)
                             : (knew + (size_t)b * 1024 + (hh - 32) * 128);
    dst[tid] = o1;
    dst[tid + 64] = o2;
  }
}

// ---------------------------------------------------------------------------
// Kernel 3: paged GQA decode attention, KV-split, contiguous streaming.
// grid = B * ASPLIT = 1024 blocks (4/CU); 512 threads = 8 waves = 8 KV heads.
// __launch_bounds__(512, 8): 8 waves/SIMD = 4 blocks/CU = 32 waves/CU = 100%
// occupancy (VGPR = 64 from R8 measurement). unroll 2 keeps VGPR <= 64.
// Scores bounded (|q.k|*scale <= ~11.4) -> no max tracking needed.
// ---------------------------------------------------------------------------
__global__ __launch_bounds__(512, 8) void attn_decode(
    const float* __restrict__ qf, const float* __restrict__ knew,
    const float* __restrict__ vnew, const float* __restrict__ kc,
    const float* __restrict__ vc, const int* __restrict__ block_tables,
    const int* __restrict__ slot_mapping, const int* __restrict__ context_lens,
    float* __restrict__ pacc, float* __restrict__ pls) {
  const int b   = blockIdx.x >> 5;
  const int sp  = blockIdx.x & 31;
  const int tid = threadIdx.x;
  const int w   = tid >> 6;        // kv head 0..7
  const int lane = tid & 63;
  const int gi  = lane >> 4;       // position-in-quad 0..3
  const int l16 = lane & 15;
  const int d0  = l16 * 8;

  const int ctx   = context_lens[b];
  const int fslot = slot_mapping[b];
  const int base  = sp * APOS_;    // 64-pos chunk, always within one 256-page

  const int page  = block_tables[b * NBPS_ + (base >> 8)];
  const int slot0 = (page << 8) + (base & 255);
  const int rel   = fslot - slot0;
  const bool hasf = (rel >= 0) && (rel < APOS_);
  const int nv    = min(APOS_, ctx - base);

  const float scale = 0.08838834764831845f;  // 1/sqrt(128)
  float q[4][8];
  #pragma unroll
  for (int g = 0; g < 4; ++g) {
    const float4* qp = (const float4*)(qf + ((size_t)b * H_ + w * G_ + g) * HD_ + d0);
    float4 a = qp[0], c = qp[1];
    q[g][0] = a.x * scale; q[g][1] = a.y * scale; q[g][2] = a.z * scale; q[g][3] = a.w * scale;
    q[g][4] = c.x * scale; q[g][5] = c.y * scale; q[g][6] = c.z * scale; q[g][7] = c.w * scale;
  }

  const float* knp = knew + ((size_t)b * HKV_ + w) * HD_ + d0;
  const float* vnp = vnew + ((size_t)b * HKV_ + w) * HD_ + d0;
  const float* kcb = kc + ((size_t)slot0 * HKV_ + w) * HD_ + d0;
  const float* vcb = vc + ((size_t)slot0 * HKV_ + w) * HD_ + d0;

  float ls[4] = {0.f, 0.f, 0.f, 0.f};
  float acc[4][8];
  #pragma unroll
  for (int g = 0; g < 4; ++g)
    #pragma unroll
    for (int j = 0; j < 8; ++j) acc[g][j] = 0.f;

  #define ATTN_STEP(K1, K2, V1, V2, SGN)                                  \
    {                                                                     \
      float kk8[8] = {K1.x, K1.y, K1.z, K1.w, K2.x, K2.y, K2.z, K2.w};    \
      float vv[8]  = {V1.x, V1.y, V1.z, V1.w, V2.x, V2.y, V2.z, V2.w};    \
      float s[4];                                                         \
      _Pragma("unroll")                                                   \
      for (int g = 0; g < 4; ++g) {                                       \
        float t = 0.f;                                                    \
        _Pragma("unroll")                                                 \
        for (int j = 0; j < 8; ++j) t = fmaf(q[g][j], kk8[j], t);         \
        s[g] = t;                                                         \
      }                                                                   \
      _Pragma("unroll")                                                   \
      for (int o2 = 1; o2 < 16; o2 <<= 1) {                               \
        _Pragma("unroll")                                                 \
        for (int g = 0; g < 4; ++g) s[g] += __shfl_xor(s[g], o2);         \
      }                                                                   \
      _Pragma("unroll")                                                   \
      for (int g = 0; g < 4; ++g) {                                       \
        float pw = (SGN) * __expf(s[g]);                                  \
        ls[g] += pw;                                                      \
        _Pragma("unroll")                                                 \
        for (int j = 0; j < 8; ++j) acc[g][j] = fmaf(pw, vv[j], acc[g][j]); \
      }                                                                   \
    }

  if (nv == APOS_) {
    // uniform fast path: contiguous nontemporal stream, no branches
    #pragma unroll 2
    for (int it = 0; it < APOS_ / 4; ++it) {
      const int off = it * 4 + gi;
      const vf4* kp4 = (const vf4*)(kcb + (size_t)off * (HKV_ * HD_));
      const vf4* vp4 = (const vf4*)(vcb + (size_t)off * (HKV_ * HD_));
      vf4 k1 = __builtin_nontemporal_load(kp4);
      vf4 k2 = __builtin_nontemporal_load(kp4 + 1);
      vf4 v1 = __builtin_nontemporal_load(vp4);
      vf4 v2 = __builtin_nontemporal_load(vp4 + 1);
      ATTN_STEP(k1, k2, v1, v2, 1.f)
    }
    // epilogue fixup for the fresh slot
    if (hasf && gi == (rel & 3)) {
      const float* kps = kcb + (size_t)rel * (HKV_ * HD_);
      const float* vps = vcb + (size_t)rel * (HKV_ * HD_);
      float4 k1 = ((const float4*)kps)[0];
      float4 k2 = ((const float4*)kps)[1];
      float4 v1 = ((const float4*)vps)[0];
      float4 v2 = ((const float4*)vps)[1];
      ATTN_STEP(k1, k2, v1, v2, -1.f)   // subtract stale
      float4 f1 = ((const float4*)knp)[0];
      float4 f2 = ((const float4*)knp)[1];
      float4 g1 = ((const float4*)vnp)[0];
      float4 g2 = ((const float4*)vnp)[1];
      ATTN_STEP(f1, f2, g1, g2, 1.f)    // add fresh
    }
  } else {
    // general guarded path (not taken for this problem's inputs)
    for (int it = 0; it < APOS_ / 4; ++it) {
      const int off = it * 4 + gi;
      if (base + off < ctx) {
        const float* kp = (off == rel) ? knp : (kcb + (size_t)off * (HKV_ * HD_));
        const float* vp = (off == rel) ? vnp : (vcb + (size_t)off * (HKV_ * HD_));
        float4 k1 = ((const float4*)kp)[0];
        float4 k2 = ((const float4*)kp)[1];
        float4 v1 = ((const float4*)vp)[0];
        float4 v2 = ((const float4*)vp)[1];
        ATTN_STEP(k1, k2, v1, v2, 1.f)
      }
    }
  }
  #undef ATTN_STEP

  // sum the 4 position-groups within the wave
  #pragma unroll
  for (int o2 = 16; o2 < 64; o2 <<= 1) {
    #pragma unroll
    for (int g = 0; g < 4; ++g) {
      ls[g] += __shfl_xor(ls[g], o2);
      #pragma unroll
      for (int j = 0; j < 8; ++j) acc[g][j] += __shfl_xor(acc[g][j], o2);
    }
  }

  if (gi == 0) {
    #pragma unroll
    for (int g = 0; g < 4; ++g) {
      float* dst = pacc + (((size_t)sp * B_ + b) * H_ + (w * G_ + g)) * HD_ + d0;
      float4 o1 = {acc[g][0], acc[g][1], acc[g][2], acc[g][3]};
      float4 o2 = {acc[g][4], acc[g][5], acc[g][6], acc[g][7]};
      ((float4*)dst)[0] = o1;
      ((float4*)dst)[1] = o2;
      if (l16 == 0) pls[((size_t)sp * B_ + b) * H_ + (w * G_ + g)] = ls[g];
    }
  }
}

// ---------------------------------------------------------------------------
// Kernel 3b: merge KV-split partials -> attnT[k = h*128+d][m = b].
// grid = 128 x 256; loops over 32 splits.
// ---------------------------------------------------------------------------
__global__ __launch_bounds__(256) void attn_mergeT(
    const float* __restrict__ pacc, const float* __restrict__ pls,
    float* __restrict__ attnT) {
  const int idx = blockIdx.x * 256 + threadIdx.x;  // float4 index, < 32768
  const int b   = idx >> 10;
  const int h   = (idx >> 5) & 31;
  const int d4  = (idx & 31) * 4;
  const int bh  = idx >> 5;                        // b*32 + h
  const float4* p4 = (const float4*)pacc;
  float4 A = {0.f, 0.f, 0.f, 0.f};
  float L = 0.f;
  #pragma unroll
  for (int sp = 0; sp < ASPLIT_; ++sp) {
    float4 t = p4[(size_t)sp * 32768 + idx];
    A.x += t.x; A.y += t.y; A.z += t.z; A.w += t.w;
    L += pls[sp * (B_ * H_) + bh];
  }
  float r = 1.f / L;
  float* dst = attnT + ((size_t)(h * 128 + d4)) * 32 + b;
  dst[0]  = A.x * r;
  dst[32] = A.y * r;
  dst[64] = A.z * r;
  dst[96] = A.w * r;
}

// ---------------------------------------------------------------------------
// Kernel 4: output projection, split-K partials, NO LDS (R4 template).
// grid = 16 n-tiles * 16 k-splits = 256 blocks (1/CU), 512 threads.
// ---------------------------------------------------------------------------
__global__ __launch_bounds__(512) void oproj_gemm(
    const float* __restrict__ attnT, const float* __restrict__ Wo,
    float* __restrict__ P2) {
  const int tid = threadIdx.x;
  const int nid = blockIdx.x & 15;
  const int kid = blockIdx.x >> 4;
  const int k0 = kid * OKC_;

  const int ct = tid & 127;
  const int mq8 = __builtin_amdgcn_readfirstlane((tid >> 7) << 3);  // 0,8,16,24
  const int n  = nid * 256 + ct * 2;

  float2 acc[8];
  #pragma unroll
  for (int r = 0; r < 8; ++r) acc[r] = make_float2(0.f, 0.f);

  const vf2* wp = (const vf2*)(Wo + (size_t)k0 * 4096 + n);
  const vf4* ap = (const vf4*)(attnT + (size_t)k0 * 32 + mq8);

  #pragma unroll 8
  for (int kk = 0; kk < OKC_; ++kk) {
    vf2 w = __builtin_nontemporal_load(wp + (size_t)kk * 2048);
    vf4 a0 = ap[kk * 8 + 0];
    vf4 a1 = ap[kk * 8 + 1];
    #define FMA2(av, r) \
      acc[r].x = fmaf(av, w.x, acc[r].x); acc[r].y = fmaf(av, w.y, acc[r].y);
    FMA2(a0.x, 0) FMA2(a0.y, 1) FMA2(a0.z, 2) FMA2(a0.w, 3)
    FMA2(a1.x, 4) FMA2(a1.y, 5) FMA2(a1.z, 6) FMA2(a1.w, 7)
    #undef FMA2
  }

  float* o = P2 + (size_t)kid * 32 * 4096 + n;
  #pragma unroll
  for (int r = 0; r < 8; ++r) {
    int m = mq8 + r;
    *(float2*)(o + (size_t)m * 4096) = acc[r];
  }
}

// ---------------------------------------------------------------------------
// Kernel 5: reduce split-K partials of the output projection -> d_out.
// ---------------------------------------------------------------------------
__global__ __launch_bounds__(256) void oproj_reduce(
    const float* __restrict__ P2, float* __restrict__ out) {
  const int idx = blockIdx.x * 256 + threadIdx.x;  // float4 index
  const float4* p4 = (const float4*)P2;
  float4 s = {0.f, 0.f, 0.f, 0.f};
  #pragma unroll
  for (int t = 0; t < OKSPLIT_; ++t) {
    float4 v = p4[(size_t)t * 32768 + idx];
    s.x += v.x; s.y += v.y; s.z += v.z; s.w += v.w;
  }
  ((float4*)out)[idx] = s;
}

// ---------------------------------------------------------------------------
extern "C" void kernel_launch(void* const* d_in, const int* in_sizes, int n_in,
                              void* d_out, int out_size, void* d_ws, size_t ws_size,
                              hipStream_t stream) {
  const float* seqs = (const float*)d_in[0];
  const float* Wq   = (const float*)d_in[1];
  const float* Wk   = (const float*)d_in[2];
  const float* Wv   = (const float*)d_in[3];
  const float* Wo   = (const float*)d_in[4];
  const float* qn_w = (const float*)d_in[5];
  const float* kn_w = (const float*)d_in[6];
  const float* kc   = (const float*)d_in[7];
  const float* vc   = (const float*)d_in[8];
  const int* input_pos = (const int*)d_in[9];
  const int* slot_map  = (const int*)d_in[10];
  const int* btab      = (const int*)d_in[11];
  const int* ctx       = (const int*)d_in[12];
  float* out = (float*)d_out;

  char* w = (char*)d_ws;
  float* seqsT = (float*)(w);                    //      524,288
  float* P1    = (float*)(w + 524288);           //   25,165,824 (32 splits)
  float* qf    = (float*)(w + 25690112);         //      524,288
  float* knew  = (float*)(w + 26214400);         //      131,072
  float* vnew  = (float*)(w + 26345472);         //      131,072
  float* attnT = (float*)(w + 26476544);         //      524,288
  float* pacc  = (float*)(w + 27000832);         //   16,777,216 (32 splits)
  float* pls   = (float*)(w + 43778048);         //      131,072 (32 splits)
  float* P2    = (float*)(w + 43909120);         //   16,777,216 (16 splits)

  transpose32<<<64, 256, 0, stream>>>(seqs, seqsT);
  qkv_gemm<<<24 * QKSPLIT_, 256, 0, stream>>>(seqsT, Wq, Wk, Wv, P1);
  reduce_norm_rope<<<B_ * 48, 128, 0, stream>>>(P1, qn_w, kn_w, input_pos, qf, knew, vnew);
  attn_decode<<<B_ * ASPLIT_, 512, 0, stream>>>(qf, knew, vnew, kc, vc, btab, slot_map, ctx, pacc, pls);
  attn_mergeT<<<128, 256, 0, stream>>>(pacc, pls, attnT);
  oproj_gemm<<<16 * OKSPLIT_, 512, 0, stream>>>(attnT, Wo, P2);
  oproj_reduce<<<128, 256, 0, stream>>>(P2, out);
}

// Round 10
// 205.854 us; speedup vs baseline: 2.0410x; 1.9500x over previous
//
#include <hip/hip_runtime.h>
#include <hip/hip_bf16.h>
#include <math.h>

// Problem constants
#define B_     32
#define DM_    4096
#define H_     32
#define HKV_   8
#define G_     4
#define HD_    128
#define KVLEN_ 2048
#define NBPS_  8
#define NQKV_  6144   // 4096 q + 1024 k + 1024 v
#define QKSPLIT_ 32   // qkv split-K  (grid 24*32=768 = 3/CU exact)
#define QKC_     128  // 4096 / 32
#define OKSPLIT_ 16   // oproj split-K (grid 16*16=256 = 1/CU exact)
#define OKC_     256  // 4096 / 16
#define ASPLIT_ 32    // attention KV-split: 32*32=1024 blocks = 4/CU exact
#define APOS_  64     // positions per attention block (KVLEN/ASPLIT)

typedef float vf4 __attribute__((ext_vector_type(4)));
typedef float vf2 __attribute__((ext_vector_type(2)));

// ---------------------------------------------------------------------------
// Kernel 0: transpose [32][4096] -> [4096][32]. grid = 64 blocks, 256 thr.
// ---------------------------------------------------------------------------
__global__ __launch_bounds__(256) void transpose32(
    const float* __restrict__ in, float* __restrict__ out) {
  __shared__ float t[32][65];
  const int tid = threadIdx.x;
  const int k0 = blockIdx.x * 64;
  #pragma unroll
  for (int it = 0; it < 8; ++it) {
    int m = it * 4 + (tid >> 6);
    int k = tid & 63;
    t[m][k] = in[(size_t)m * DM_ + k0 + k];
  }
  __syncthreads();
  #pragma unroll
  for (int it = 0; it < 8; ++it) {
    int flat = it * 256 + tid;
    out[(size_t)k0 * 32 + flat] = t[flat & 31][flat >> 5];
  }
}

// ---------------------------------------------------------------------------
// Kernel 1: fused QKV projection, split-K partials, NO LDS (R4 template).
// grid = 24 n-tiles * 32 k-splits = 768 blocks (3/CU), 256 threads.
// ---------------------------------------------------------------------------
__global__ __launch_bounds__(256) void qkv_gemm(
    const float* __restrict__ seqsT, const float* __restrict__ Wq,
    const float* __restrict__ Wk, const float* __restrict__ Wv,
    float* __restrict__ P1) {
  const int tid = threadIdx.x;
  const int nid = blockIdx.x % 24;
  const int kid = blockIdx.x / 24;
  const int k0 = kid * QKC_;

  const int ct = tid & 127;
  const int mh16 = __builtin_amdgcn_readfirstlane((tid >> 7) << 4);  // 0 or 16
  const int n  = nid * 256 + ct * 2;

  const float* W; int col, ldw;
  if (nid < 16)      { W = Wq; col = n;        ldw = 4096; }
  else if (nid < 20) { W = Wk; col = n - 4096; ldw = 1024; }
  else               { W = Wv; col = n - 5120; ldw = 1024; }

  float2 acc[16];
  #pragma unroll
  for (int r = 0; r < 16; ++r) acc[r] = make_float2(0.f, 0.f);

  const vf2* wp = (const vf2*)(W + (size_t)k0 * ldw + col);
  const int ldw2 = ldw >> 1;
  const vf4* ap = (const vf4*)(seqsT + (size_t)k0 * 32 + mh16);

  #pragma unroll 8
  for (int kk = 0; kk < QKC_; ++kk) {
    vf2 w = __builtin_nontemporal_load(wp + (size_t)kk * ldw2);
    vf4 a0 = ap[kk * 8 + 0];
    vf4 a1 = ap[kk * 8 + 1];
    vf4 a2 = ap[kk * 8 + 2];
    vf4 a3 = ap[kk * 8 + 3];
    #define FMA2(av, r) \
      acc[r].x = fmaf(av, w.x, acc[r].x); acc[r].y = fmaf(av, w.y, acc[r].y);
    FMA2(a0.x, 0)  FMA2(a0.y, 1)  FMA2(a0.z, 2)  FMA2(a0.w, 3)
    FMA2(a1.x, 4)  FMA2(a1.y, 5)  FMA2(a1.z, 6)  FMA2(a1.w, 7)
    FMA2(a2.x, 8)  FMA2(a2.y, 9)  FMA2(a2.z, 10) FMA2(a2.w, 11)
    FMA2(a3.x, 12) FMA2(a3.y, 13) FMA2(a3.z, 14) FMA2(a3.w, 15)
    #undef FMA2
  }

  float* o = P1 + (size_t)kid * 32 * NQKV_ + n;
  #pragma unroll
  for (int r = 0; r < 16; ++r) {
    int m = mh16 + r;
    *(float2*)(o + (size_t)m * NQKV_) = acc[r];
  }
}

// ---------------------------------------------------------------------------
// Kernel 2: reduce split-K partials, RMSNorm (q,k), RoPE (q,k).
// ---------------------------------------------------------------------------
__global__ __launch_bounds__(128) void reduce_norm_rope(
    const float* __restrict__ P1, const float* __restrict__ qn_w,
    const float* __restrict__ kn_w, const int* __restrict__ input_pos,
    float* __restrict__ qf, float* __restrict__ knew, float* __restrict__ vnew) {
  const int b = blockIdx.x / 48;
  const int hh = blockIdx.x % 48;
  const int tid = threadIdx.x;

  int col0, kind;  // 0=q,1=k,2=v
  if (hh < 32)      { kind = 0; col0 = hh * 128; }
  else if (hh < 40) { kind = 1; col0 = 4096 + (hh - 32) * 128; }
  else              { kind = 2; col0 = 5120 + (hh - 40) * 128; }

  float x = 0.f;
  const float* p = P1 + (size_t)b * NQKV_ + col0 + tid;
  #pragma unroll
  for (int s = 0; s < QKSPLIT_; ++s) x += p[(size_t)s * 32 * NQKV_];

  if (kind == 2) {
    vnew[(size_t)b * 1024 + (hh - 40) * 128 + tid] = x;
    return;
  }

  __shared__ float lds[128];
  __shared__ float wred[2];
  float ss = x * x;
  #pragma unroll
  for (int off = 32; off > 0; off >>= 1) ss += __shfl_down(ss, off);
  if ((tid & 63) == 0) wred[tid >> 6] = ss;
  __syncthreads();
  float tot = wred[0] + wred[1];
  float r = rsqrtf(tot * (1.f / 128.f) + 1e-6f);
  const float* wv = (kind == 0) ? qn_w : kn_w;
  x = x * r * wv[tid];

  lds[tid] = x;
  __syncthreads();

  if (tid < 64) {
    float pos = (float)input_pos[b];
    float inv = exp2f(-(float)tid * 0.20762050593045952f);
    float ang = pos * inv;
    float c = cosf(ang), s = sinf(ang);
    float x1 = lds[tid], x2 = lds[tid + 64];
    float o1 = x1 * c - x2 * s;
    float o2 = x2 * c + x1 * s;
    float* dst = (kind == 0) ? (qf + (size_t)b * 4096 + hh * 128)
                             : (knew + (size_t)b * 1024 + (hh - 32) * 128);
    dst[tid] = o1;
    dst[tid + 64] = o2;
  }
}

// ---------------------------------------------------------------------------
// Kernel 3: paged GQA decode attention, KV-split, contiguous streaming.
// grid = B * ASPLIT = 1024 blocks (4/CU); 512 threads = 8 waves = 8 KV heads.
// __launch_bounds__(512, 4): R8 measured VGPR=64 (no spills) under this
// bound, and VGPR=64 already permits 8 waves/SIMD in HW -> the 1024-block
// grid can fill 32 waves/CU. (512,8) forced VGPR=32 and spilled: R9 showed
// WRITE_SIZE 261 MB, dur 320 us. Do NOT raise the bound.
// Scores bounded (|q.k|*scale <= ~11.4) -> no max tracking needed.
// ---------------------------------------------------------------------------
__global__ __launch_bounds__(512, 4) void attn_decode(
    const float* __restrict__ qf, const float* __restrict__ knew,
    const float* __restrict__ vnew, const float* __restrict__ kc,
    const float* __restrict__ vc, const int* __restrict__ block_tables,
    const int* __restrict__ slot_mapping, const int* __restrict__ context_lens,
    float* __restrict__ pacc, float* __restrict__ pls) {
  const int b   = blockIdx.x >> 5;
  const int sp  = blockIdx.x & 31;
  const int tid = threadIdx.x;
  const int w   = tid >> 6;        // kv head 0..7
  const int lane = tid & 63;
  const int gi  = lane >> 4;       // position-in-quad 0..3
  const int l16 = lane & 15;
  const int d0  = l16 * 8;

  const int ctx   = context_lens[b];
  const int fslot = slot_mapping[b];
  const int base  = sp * APOS_;    // 64-pos chunk, always within one 256-page

  const int page  = block_tables[b * NBPS_ + (base >> 8)];
  const int slot0 = (page << 8) + (base & 255);
  const int rel   = fslot - slot0;
  const bool hasf = (rel >= 0) && (rel < APOS_);
  const int nv    = min(APOS_, ctx - base);

  const float scale = 0.08838834764831845f;  // 1/sqrt(128)
  float q[4][8];
  #pragma unroll
  for (int g = 0; g < 4; ++g) {
    const float4* qp = (const float4*)(qf + ((size_t)b * H_ + w * G_ + g) * HD_ + d0);
    float4 a = qp[0], c = qp[1];
    q[g][0] = a.x * scale; q[g][1] = a.y * scale; q[g][2] = a.z * scale; q[g][3] = a.w * scale;
    q[g][4] = c.x * scale; q[g][5] = c.y * scale; q[g][6] = c.z * scale; q[g][7] = c.w * scale;
  }

  const float* knp = knew + ((size_t)b * HKV_ + w) * HD_ + d0;
  const float* vnp = vnew + ((size_t)b * HKV_ + w) * HD_ + d0;
  const float* kcb = kc + ((size_t)slot0 * HKV_ + w) * HD_ + d0;
  const float* vcb = vc + ((size_t)slot0 * HKV_ + w) * HD_ + d0;

  float ls[4] = {0.f, 0.f, 0.f, 0.f};
  float acc[4][8];
  #pragma unroll
  for (int g = 0; g < 4; ++g)
    #pragma unroll
    for (int j = 0; j < 8; ++j) acc[g][j] = 0.f;

  #define ATTN_STEP(K1, K2, V1, V2, SGN)                                  \
    {                                                                     \
      float kk8[8] = {K1.x, K1.y, K1.z, K1.w, K2.x, K2.y, K2.z, K2.w};    \
      float vv[8]  = {V1.x, V1.y, V1.z, V1.w, V2.x, V2.y, V2.z, V2.w};    \
      float s[4];                                                         \
      _Pragma("unroll")                                                   \
      for (int g = 0; g < 4; ++g) {                                       \
        float t = 0.f;                                                    \
        _Pragma("unroll")                                                 \
        for (int j = 0; j < 8; ++j) t = fmaf(q[g][j], kk8[j], t);         \
        s[g] = t;                                                         \
      }                                                                   \
      _Pragma("unroll")                                                   \
      for (int o2 = 1; o2 < 16; o2 <<= 1) {                               \
        _Pragma("unroll")                                                 \
        for (int g = 0; g < 4; ++g) s[g] += __shfl_xor(s[g], o2);         \
      }                                                                   \
      _Pragma("unroll")                                                   \
      for (int g = 0; g < 4; ++g) {                                       \
        float pw = (SGN) * __expf(s[g]);                                  \
        ls[g] += pw;                                                      \
        _Pragma("unroll")                                                 \
        for (int j = 0; j < 8; ++j) acc[g][j] = fmaf(pw, vv[j], acc[g][j]); \
      }                                                                   \
    }

  if (nv == APOS_) {
    // uniform fast path: contiguous nontemporal stream, no branches
    #pragma unroll 2
    for (int it = 0; it < APOS_ / 4; ++it) {
      const int off = it * 4 + gi;
      const vf4* kp4 = (const vf4*)(kcb + (size_t)off * (HKV_ * HD_));
      const vf4* vp4 = (const vf4*)(vcb + (size_t)off * (HKV_ * HD_));
      vf4 k1 = __builtin_nontemporal_load(kp4);
      vf4 k2 = __builtin_nontemporal_load(kp4 + 1);
      vf4 v1 = __builtin_nontemporal_load(vp4);
      vf4 v2 = __builtin_nontemporal_load(vp4 + 1);
      ATTN_STEP(k1, k2, v1, v2, 1.f)
    }
    // epilogue fixup for the fresh slot
    if (hasf && gi == (rel & 3)) {
      const float* kps = kcb + (size_t)rel * (HKV_ * HD_);
      const float* vps = vcb + (size_t)rel * (HKV_ * HD_);
      float4 k1 = ((const float4*)kps)[0];
      float4 k2 = ((const float4*)kps)[1];
      float4 v1 = ((const float4*)vps)[0];
      float4 v2 = ((const float4*)vps)[1];
      ATTN_STEP(k1, k2, v1, v2, -1.f)   // subtract stale
      float4 f1 = ((const float4*)knp)[0];
      float4 f2 = ((const float4*)knp)[1];
      float4 g1 = ((const float4*)vnp)[0];
      float4 g2 = ((const float4*)vnp)[1];
      ATTN_STEP(f1, f2, g1, g2, 1.f)    // add fresh
    }
  } else {
    // general guarded path (not taken for this problem's inputs)
    for (int it = 0; it < APOS_ / 4; ++it) {
      const int off = it * 4 + gi;
      if (base + off < ctx) {
        const float* kp = (off == rel) ? knp : (kcb + (size_t)off * (HKV_ * HD_));
        const float* vp = (off == rel) ? vnp : (vcb + (size_t)off * (HKV_ * HD_));
        float4 k1 = ((const float4*)kp)[0];
        float4 k2 = ((const float4*)kp)[1];
        float4 v1 = ((const float4*)vp)[0];
        float4 v2 = ((const float4*)vp)[1];
        ATTN_STEP(k1, k2, v1, v2, 1.f)
      }
    }
  }
  #undef ATTN_STEP

  // sum the 4 position-groups within the wave
  #pragma unroll
  for (int o2 = 16; o2 < 64; o2 <<= 1) {
    #pragma unroll
    for (int g = 0; g < 4; ++g) {
      ls[g] += __shfl_xor(ls[g], o2);
      #pragma unroll
      for (int j = 0; j < 8; ++j) acc[g][j] += __shfl_xor(acc[g][j], o2);
    }
  }

  if (gi == 0) {
    #pragma unroll
    for (int g = 0; g < 4; ++g) {
      float* dst = pacc + (((size_t)sp * B_ + b) * H_ + (w * G_ + g)) * HD_ + d0;
      float4 o1 = {acc[g][0], acc[g][1], acc[g][2], acc[g][3]};
      float4 o2 = {acc[g][4], acc[g][5], acc[g][6], acc[g][7]};
      ((float4*)dst)[0] = o1;
      ((float4*)dst)[1] = o2;
      if (l16 == 0) pls[((size_t)sp * B_ + b) * H_ + (w * G_ + g)] = ls[g];
    }
  }
}

// ---------------------------------------------------------------------------
// Kernel 3b: merge KV-split partials -> attnT[k = h*128+d][m = b].
// grid = 128 x 256; loops over 32 splits.
// ---------------------------------------------------------------------------
__global__ __launch_bounds__(256) void attn_mergeT(
    const float* __restrict__ pacc, const float* __restrict__ pls,
    float* __restrict__ attnT) {
  const int idx = blockIdx.x * 256 + threadIdx.x;  // float4 index, < 32768
  const int b   = idx >> 10;
  const int h   = (idx >> 5) & 31;
  const int d4  = (idx & 31) * 4;
  const int bh  = idx >> 5;                        // b*32 + h
  const float4* p4 = (const float4*)pacc;
  float4 A = {0.f, 0.f, 0.f, 0.f};
  float L = 0.f;
  #pragma unroll
  for (int sp = 0; sp < ASPLIT_; ++sp) {
    float4 t = p4[(size_t)sp * 32768 + idx];
    A.x += t.x; A.y += t.y; A.z += t.z; A.w += t.w;
    L += pls[sp * (B_ * H_) + bh];
  }
  float r = 1.f / L;
  float* dst = attnT + ((size_t)(h * 128 + d4)) * 32 + b;
  dst[0]  = A.x * r;
  dst[32] = A.y * r;
  dst[64] = A.z * r;
  dst[96] = A.w * r;
}

// ---------------------------------------------------------------------------
// Kernel 4: output projection, split-K partials, NO LDS (R4 template).
// grid = 16 n-tiles * 16 k-splits = 256 blocks (1/CU), 512 threads.
// ---------------------------------------------------------------------------
__global__ __launch_bounds__(512) void oproj_gemm(
    const float* __restrict__ attnT, const float* __restrict__ Wo,
    float* __restrict__ P2) {
  const int tid = threadIdx.x;
  const int nid = blockIdx.x & 15;
  const int kid = blockIdx.x >> 4;
  const int k0 = kid * OKC_;

  const int ct = tid & 127;
  const int mq8 = __builtin_amdgcn_readfirstlane((tid >> 7) << 3);  // 0,8,16,24
  const int n  = nid * 256 + ct * 2;

  float2 acc[8];
  #pragma unroll
  for (int r = 0; r < 8; ++r) acc[r] = make_float2(0.f, 0.f);

  const vf2* wp = (const vf2*)(Wo + (size_t)k0 * 4096 + n);
  const vf4* ap = (const vf4*)(attnT + (size_t)k0 * 32 + mq8);

  #pragma unroll 8
  for (int kk = 0; kk < OKC_; ++kk) {
    vf2 w = __builtin_nontemporal_load(wp + (size_t)kk * 2048);
    vf4 a0 = ap[kk * 8 + 0];
    vf4 a1 = ap[kk * 8 + 1];
    #define FMA2(av, r) \
      acc[r].x = fmaf(av, w.x, acc[r].x); acc[r].y = fmaf(av, w.y, acc[r].y);
    FMA2(a0.x, 0) FMA2(a0.y, 1) FMA2(a0.z, 2) FMA2(a0.w, 3)
    FMA2(a1.x, 4) FMA2(a1.y, 5) FMA2(a1.z, 6) FMA2(a1.w, 7)
    #undef FMA2
  }

  float* o = P2 + (size_t)kid * 32 * 4096 + n;
  #pragma unroll
  for (int r = 0; r < 8; ++r) {
    int m = mq8 + r;
    *(float2*)(o + (size_t)m * 4096) = acc[r];
  }
}

// ---------------------------------------------------------------------------
// Kernel 5: reduce split-K partials of the output projection -> d_out.
// ---------------------------------------------------------------------------
__global__ __launch_bounds__(256) void oproj_reduce(
    const float* __restrict__ P2, float* __restrict__ out) {
  const int idx = blockIdx.x * 256 + threadIdx.x;  // float4 index
  const float4* p4 = (const float4*)P2;
  float4 s = {0.f, 0.f, 0.f, 0.f};
  #pragma unroll
  for (int t = 0; t < OKSPLIT_; ++t) {
    float4 v = p4[(size_t)t * 32768 + idx];
    s.x += v.x; s.y += v.y; s.z += v.z; s.w += v.w;
  }
  ((float4*)out)[idx] = s;
}

// ---------------------------------------------------------------------------
extern "C" void kernel_launch(void* const* d_in, const int* in_sizes, int n_in,
                              void* d_out, int out_size, void* d_ws, size_t ws_size,
                              hipStream_t stream) {
  const float* seqs = (const float*)d_in[0];
  const float* Wq   = (const float*)d_in[1];
  const float* Wk   = (const float*)d_in[2];
  const float* Wv   = (const float*)d_in[3];
  const float* Wo   = (const float*)d_in[4];
  const float* qn_w = (const float*)d_in[5];
  const float* kn_w = (const float*)d_in[6];
  const float* kc   = (const float*)d_in[7];
  const float* vc   = (const float*)d_in[8];
  const int* input_pos = (const int*)d_in[9];
  const int* slot_map  = (const int*)d_in[10];
  const int* btab      = (const int*)d_in[11];
  const int* ctx       = (const int*)d_in[12];
  float* out = (float*)d_out;

  char* w = (char*)d_ws;
  float* seqsT = (float*)(w);                    //      524,288
  float* P1    = (float*)(w + 524288);           //   25,165,824 (32 splits)
  float* qf    = (float*)(w + 25690112);         //      524,288
  float* knew  = (float*)(w + 26214400);         //      131,072
  float* vnew  = (float*)(w + 26345472);         //      131,072
  float* attnT = (float*)(w + 26476544);         //      524,288
  float* pacc  = (float*)(w + 27000832);         //   16,777,216 (32 splits)
  float* pls   = (float*)(w + 43778048);         //      131,072 (32 splits)
  float* P2    = (float*)(w + 43909120);         //   16,777,216 (16 splits)

  transpose32<<<64, 256, 0, stream>>>(seqs, seqsT);
  qkv_gemm<<<24 * QKSPLIT_, 256, 0, stream>>>(seqsT, Wq, Wk, Wv, P1);
  reduce_norm_rope<<<B_ * 48, 128, 0, stream>>>(P1, qn_w, kn_w, input_pos, qf, knew, vnew);
  attn_decode<<<B_ * ASPLIT_, 512, 0, stream>>>(qf, knew, vnew, kc, vc, btab, slot_map, ctx, pacc, pls);
  attn_mergeT<<<128, 256, 0, stream>>>(pacc, pls, attnT);
  oproj_gemm<<<16 * OKSPLIT_, 512, 0, stream>>>(attnT, Wo, P2);
  oproj_reduce<<<128, 256, 0, stream>>>(P2, out);
}

// Round 11
// 185.120 us; speedup vs baseline: 2.2696x; 1.1120x over previous
//
#include <hip/hip_runtime.h>
#include <hip/hip_bf16.h>
#include <math.h>

// Problem constants
#define B_     32
#define DM_    4096
#define H_     32
#define HKV_   8
#define G_     4
#define HD_    128
#define KVLEN_ 2048
#define NBPS_  8
#define NQKV_  6144   // 4096 q + 1024 k + 1024 v
#define QKSPLIT_ 32   // qkv split-K  (grid 24*32=768 = 3/CU exact)
#define QKC_     128  // 4096 / 32
#define OKSPLIT_ 32   // oproj split-K (grid 16*32=512 = 2/CU exact)
#define OKC_     128  // 4096 / 32
#define ASPLIT_ 16    // attention KV-split (R7 proven: 512 blocks, 113 us)
#define APOS_  128    // positions per attention block

typedef float vf4 __attribute__((ext_vector_type(4)));
typedef float vf2 __attribute__((ext_vector_type(2)));

// ---------------------------------------------------------------------------
// Kernel 0: transpose [32][4096] -> [4096][32]. grid = 64 blocks, 256 thr.
// ---------------------------------------------------------------------------
__global__ __launch_bounds__(256) void transpose32(
    const float* __restrict__ in, float* __restrict__ out) {
  __shared__ float t[32][65];
  const int tid = threadIdx.x;
  const int k0 = blockIdx.x * 64;
  #pragma unroll
  for (int it = 0; it < 8; ++it) {
    int m = it * 4 + (tid >> 6);
    int k = tid & 63;
    t[m][k] = in[(size_t)m * DM_ + k0 + k];
  }
  __syncthreads();
  #pragma unroll
  for (int it = 0; it < 8; ++it) {
    int flat = it * 256 + tid;
    out[(size_t)k0 * 32 + flat] = t[flat & 31][flat >> 5];
  }
}

// ---------------------------------------------------------------------------
// Kernel 1: fused QKV projection, split-K partials, NO LDS (R4 template).
// grid = 24 n-tiles * 32 k-splits = 768 blocks (3/CU), 256 threads.
// ---------------------------------------------------------------------------
__global__ __launch_bounds__(256) void qkv_gemm(
    const float* __restrict__ seqsT, const float* __restrict__ Wq,
    const float* __restrict__ Wk, const float* __restrict__ Wv,
    float* __restrict__ P1) {
  const int tid = threadIdx.x;
  const int nid = blockIdx.x % 24;
  const int kid = blockIdx.x / 24;
  const int k0 = kid * QKC_;

  const int ct = tid & 127;
  const int mh16 = __builtin_amdgcn_readfirstlane((tid >> 7) << 4);  // 0 or 16
  const int n  = nid * 256 + ct * 2;

  const float* W; int col, ldw;
  if (nid < 16)      { W = Wq; col = n;        ldw = 4096; }
  else if (nid < 20) { W = Wk; col = n - 4096; ldw = 1024; }
  else               { W = Wv; col = n - 5120; ldw = 1024; }

  float2 acc[16];
  #pragma unroll
  for (int r = 0; r < 16; ++r) acc[r] = make_float2(0.f, 0.f);

  const vf2* wp = (const vf2*)(W + (size_t)k0 * ldw + col);
  const int ldw2 = ldw >> 1;
  const vf4* ap = (const vf4*)(seqsT + (size_t)k0 * 32 + mh16);

  #pragma unroll 8
  for (int kk = 0; kk < QKC_; ++kk) {
    vf2 w = __builtin_nontemporal_load(wp + (size_t)kk * ldw2);
    vf4 a0 = ap[kk * 8 + 0];
    vf4 a1 = ap[kk * 8 + 1];
    vf4 a2 = ap[kk * 8 + 2];
    vf4 a3 = ap[kk * 8 + 3];
    #define FMA2(av, r) \
      acc[r].x = fmaf(av, w.x, acc[r].x); acc[r].y = fmaf(av, w.y, acc[r].y);
    FMA2(a0.x, 0)  FMA2(a0.y, 1)  FMA2(a0.z, 2)  FMA2(a0.w, 3)
    FMA2(a1.x, 4)  FMA2(a1.y, 5)  FMA2(a1.z, 6)  FMA2(a1.w, 7)
    FMA2(a2.x, 8)  FMA2(a2.y, 9)  FMA2(a2.z, 10) FMA2(a2.w, 11)
    FMA2(a3.x, 12) FMA2(a3.y, 13) FMA2(a3.z, 14) FMA2(a3.w, 15)
    #undef FMA2
  }

  float* o = P1 + (size_t)kid * 32 * NQKV_ + n;
  #pragma unroll
  for (int r = 0; r < 16; ++r) {
    int m = mh16 + r;
    *(float2*)(o + (size_t)m * NQKV_) = acc[r];
  }
}

// ---------------------------------------------------------------------------
// Kernel 2: reduce split-K partials, RMSNorm (q,k), RoPE (q,k).
// ---------------------------------------------------------------------------
__global__ __launch_bounds__(128) void reduce_norm_rope(
    const float* __restrict__ P1, const float* __restrict__ qn_w,
    const float* __restrict__ kn_w, const int* __restrict__ input_pos,
    float* __restrict__ qf, float* __restrict__ knew, float* __restrict__ vnew) {
  const int b = blockIdx.x / 48;
  const int hh = blockIdx.x % 48;
  const int tid = threadIdx.x;

  int col0, kind;  // 0=q,1=k,2=v
  if (hh < 32)      { kind = 0; col0 = hh * 128; }
  else if (hh < 40) { kind = 1; col0 = 4096 + (hh - 32) * 128; }
  else              { kind = 2; col0 = 5120 + (hh - 40) * 128; }

  float x = 0.f;
  const float* p = P1 + (size_t)b * NQKV_ + col0 + tid;
  #pragma unroll
  for (int s = 0; s < QKSPLIT_; ++s) x += p[(size_t)s * 32 * NQKV_];

  if (kind == 2) {
    vnew[(size_t)b * 1024 + (hh - 40) * 128 + tid] = x;
    return;
  }

  __shared__ float lds[128];
  __shared__ float wred[2];
  float ss = x * x;
  #pragma unroll
  for (int off = 32; off > 0; off >>= 1) ss += __shfl_down(ss, off);
  if ((tid & 63) == 0) wred[tid >> 6] = ss;
  __syncthreads();
  float tot = wred[0] + wred[1];
  float r = rsqrtf(tot * (1.f / 128.f) + 1e-6f);
  const float* wv = (kind == 0) ? qn_w : kn_w;
  x = x * r * wv[tid];

  lds[tid] = x;
  __syncthreads();

  if (tid < 64) {
    float pos = (float)input_pos[b];
    float inv = exp2f(-(float)tid * 0.20762050593045952f);
    float ang = pos * inv;
    float c = cosf(ang), s = sinf(ang);
    float x1 = lds[tid], x2 = lds[tid + 64];
    float o1 = x1 * c - x2 * s;
    float o2 = x2 * c + x1 * s;
    float* dst = (kind == 0) ? (qf + (size_t)b * 4096 + hh * 128)
                             : (knew + (size_t)b * 1024 + (hh - 32) * 128);
    dst[tid] = o1;
    dst[tid + 64] = o2;
  }
}

// ---------------------------------------------------------------------------
// Kernel 3: paged GQA decode attention (R7 proven config: 113 us, VGPR=64,
// no spills). grid = B * 16 = 512 blocks; 512 threads = 8 waves = 8 KV heads.
// __launch_bounds__(512, 4); unroll 2. Scores bounded -> no max tracking.
// ---------------------------------------------------------------------------
__global__ __launch_bounds__(512, 4) void attn_decode(
    const float* __restrict__ qf, const float* __restrict__ knew,
    const float* __restrict__ vnew, const float* __restrict__ kc,
    const float* __restrict__ vc, const int* __restrict__ block_tables,
    const int* __restrict__ slot_mapping, const int* __restrict__ context_lens,
    float* __restrict__ pacc, float* __restrict__ pls) {
  const int b   = blockIdx.x >> 4;
  const int sp  = blockIdx.x & 15;
  const int tid = threadIdx.x;
  const int w   = tid >> 6;        // kv head 0..7
  const int lane = tid & 63;
  const int gi  = lane >> 4;       // position-in-quad 0..3
  const int l16 = lane & 15;
  const int d0  = l16 * 8;

  const int ctx   = context_lens[b];
  const int fslot = slot_mapping[b];
  const int base  = sp * APOS_;

  const int page  = block_tables[b * NBPS_ + (base >> 8)];
  const int slot0 = (page << 8) + (base & 255);
  const int rel   = fslot - slot0;
  const bool hasf = (rel >= 0) && (rel < APOS_);
  const int nv    = min(APOS_, ctx - base);

  const float scale = 0.08838834764831845f;  // 1/sqrt(128)
  float q[4][8];
  #pragma unroll
  for (int g = 0; g < 4; ++g) {
    const float4* qp = (const float4*)(qf + ((size_t)b * H_ + w * G_ + g) * HD_ + d0);
    float4 a = qp[0], c = qp[1];
    q[g][0] = a.x * scale; q[g][1] = a.y * scale; q[g][2] = a.z * scale; q[g][3] = a.w * scale;
    q[g][4] = c.x * scale; q[g][5] = c.y * scale; q[g][6] = c.z * scale; q[g][7] = c.w * scale;
  }

  const float* knp = knew + ((size_t)b * HKV_ + w) * HD_ + d0;
  const float* vnp = vnew + ((size_t)b * HKV_ + w) * HD_ + d0;
  const float* kcb = kc + ((size_t)slot0 * HKV_ + w) * HD_ + d0;
  const float* vcb = vc + ((size_t)slot0 * HKV_ + w) * HD_ + d0;

  float ls[4] = {0.f, 0.f, 0.f, 0.f};
  float acc[4][8];
  #pragma unroll
  for (int g = 0; g < 4; ++g)
    #pragma unroll
    for (int j = 0; j < 8; ++j) acc[g][j] = 0.f;

  #define ATTN_STEP(K1, K2, V1, V2, SGN)                                  \
    {                                                                     \
      float kk8[8] = {K1.x, K1.y, K1.z, K1.w, K2.x, K2.y, K2.z, K2.w};    \
      float vv[8]  = {V1.x, V1.y, V1.z, V1.w, V2.x, V2.y, V2.z, V2.w};    \
      float s[4];                                                         \
      _Pragma("unroll")                                                   \
      for (int g = 0; g < 4; ++g) {                                       \
        float t = 0.f;                                                    \
        _Pragma("unroll")                                                 \
        for (int j = 0; j < 8; ++j) t = fmaf(q[g][j], kk8[j], t);         \
        s[g] = t;                                                         \
      }                                                                   \
      _Pragma("unroll")                                                   \
      for (int o2 = 1; o2 < 16; o2 <<= 1) {                               \
        _Pragma("unroll")                                                 \
        for (int g = 0; g < 4; ++g) s[g] += __shfl_xor(s[g], o2);         \
      }                                                                   \
      _Pragma("unroll")                                                   \
      for (int g = 0; g < 4; ++g) {                                       \
        float pw = (SGN) * __expf(s[g]);                                  \
        ls[g] += pw;                                                      \
        _Pragma("unroll")                                                 \
        for (int j = 0; j < 8; ++j) acc[g][j] = fmaf(pw, vv[j], acc[g][j]); \
      }                                                                   \
    }

  if (nv == APOS_) {
    // uniform fast path: contiguous nontemporal stream, no branches
    #pragma unroll 2
    for (int it = 0; it < APOS_ / 4; ++it) {
      const int off = it * 4 + gi;
      const vf4* kp4 = (const vf4*)(kcb + (size_t)off * (HKV_ * HD_));
      const vf4* vp4 = (const vf4*)(vcb + (size_t)off * (HKV_ * HD_));
      vf4 k1 = __builtin_nontemporal_load(kp4);
      vf4 k2 = __builtin_nontemporal_load(kp4 + 1);
      vf4 v1 = __builtin_nontemporal_load(vp4);
      vf4 v2 = __builtin_nontemporal_load(vp4 + 1);
      ATTN_STEP(k1, k2, v1, v2, 1.f)
    }
    // epilogue fixup for the fresh slot
    if (hasf && gi == (rel & 3)) {
      const float* kps = kcb + (size_t)rel * (HKV_ * HD_);
      const float* vps = vcb + (size_t)rel * (HKV_ * HD_);
      float4 k1 = ((const float4*)kps)[0];
      float4 k2 = ((const float4*)kps)[1];
      float4 v1 = ((const float4*)vps)[0];
      float4 v2 = ((const float4*)vps)[1];
      ATTN_STEP(k1, k2, v1, v2, -1.f)   // subtract stale
      float4 f1 = ((const float4*)knp)[0];
      float4 f2 = ((const float4*)knp)[1];
      float4 g1 = ((const float4*)vnp)[0];
      float4 g2 = ((const float4*)vnp)[1];
      ATTN_STEP(f1, f2, g1, g2, 1.f)    // add fresh
    }
  } else {
    // general guarded path (not taken for this problem's inputs)
    for (int it = 0; it < APOS_ / 4; ++it) {
      const int off = it * 4 + gi;
      if (base + off < ctx) {
        const float* kp = (off == rel) ? knp : (kcb + (size_t)off * (HKV_ * HD_));
        const float* vp = (off == rel) ? vnp : (vcb + (size_t)off * (HKV_ * HD_));
        float4 k1 = ((const float4*)kp)[0];
        float4 k2 = ((const float4*)kp)[1];
        float4 v1 = ((const float4*)vp)[0];
        float4 v2 = ((const float4*)vp)[1];
        ATTN_STEP(k1, k2, v1, v2, 1.f)
      }
    }
  }
  #undef ATTN_STEP

  // sum the 4 position-groups within the wave
  #pragma unroll
  for (int o2 = 16; o2 < 64; o2 <<= 1) {
    #pragma unroll
    for (int g = 0; g < 4; ++g) {
      ls[g] += __shfl_xor(ls[g], o2);
      #pragma unroll
      for (int j = 0; j < 8; ++j) acc[g][j] += __shfl_xor(acc[g][j], o2);
    }
  }

  if (gi == 0) {
    #pragma unroll
    for (int g = 0; g < 4; ++g) {
      float* dst = pacc + (((size_t)sp * B_ + b) * H_ + (w * G_ + g)) * HD_ + d0;
      float4 o1 = {acc[g][0], acc[g][1], acc[g][2], acc[g][3]};
      float4 o2 = {acc[g][4], acc[g][5], acc[g][6], acc[g][7]};
      ((float4*)dst)[0] = o1;
      ((float4*)dst)[1] = o2;
      if (l16 == 0) pls[((size_t)sp * B_ + b) * H_ + (w * G_ + g)] = ls[g];
    }
  }
}

// ---------------------------------------------------------------------------
// Kernel 3b: merge KV-split partials -> attnT[k = h*128+d][m = b].
// grid = 128 x 256; loops over 16 splits.
// ---------------------------------------------------------------------------
__global__ __launch_bounds__(256) void attn_mergeT(
    const float* __restrict__ pacc, const float* __restrict__ pls,
    float* __restrict__ attnT) {
  const int idx = blockIdx.x * 256 + threadIdx.x;  // float4 index, < 32768
  const int b   = idx >> 10;
  const int h   = (idx >> 5) & 31;
  const int d4  = (idx & 31) * 4;
  const int bh  = idx >> 5;                        // b*32 + h
  const float4* p4 = (const float4*)pacc;
  float4 A = {0.f, 0.f, 0.f, 0.f};
  float L = 0.f;
  #pragma unroll
  for (int sp = 0; sp < ASPLIT_; ++sp) {
    float4 t = p4[(size_t)sp * 32768 + idx];
    A.x += t.x; A.y += t.y; A.z += t.z; A.w += t.w;
    L += pls[sp * (B_ * H_) + bh];
  }
  float r = 1.f / L;
  float* dst = attnT + ((size_t)(h * 128 + d4)) * 32 + b;
  dst[0]  = A.x * r;
  dst[32] = A.y * r;
  dst[64] = A.z * r;
  dst[96] = A.w * r;
}

// ---------------------------------------------------------------------------
// Kernel 4: output projection, split-K partials, NO LDS — qkv template.
// grid = 16 n-tiles * 32 k-splits = 512 blocks (2/CU), 256 threads.
// Thread: TM=16 rows x TN=2 cols; A via wave-uniform loads from attnT.
// ---------------------------------------------------------------------------
__global__ __launch_bounds__(256) void oproj_gemm(
    const float* __restrict__ attnT, const float* __restrict__ Wo,
    float* __restrict__ P2) {
  const int tid = threadIdx.x;
  const int nid = blockIdx.x & 15;
  const int kid = blockIdx.x >> 4;
  const int k0 = kid * OKC_;

  const int ct = tid & 127;
  const int mh16 = __builtin_amdgcn_readfirstlane((tid >> 7) << 4);  // 0 or 16
  const int n  = nid * 256 + ct * 2;

  float2 acc[16];
  #pragma unroll
  for (int r = 0; r < 16; ++r) acc[r] = make_float2(0.f, 0.f);

  const vf2* wp = (const vf2*)(Wo + (size_t)k0 * 4096 + n);
  const vf4* ap = (const vf4*)(attnT + (size_t)k0 * 32 + mh16);

  #pragma unroll 8
  for (int kk = 0; kk < OKC_; ++kk) {
    vf2 w = __builtin_nontemporal_load(wp + (size_t)kk * 2048);
    vf4 a0 = ap[kk * 8 + 0];
    vf4 a1 = ap[kk * 8 + 1];
    vf4 a2 = ap[kk * 8 + 2];
    vf4 a3 = ap[kk * 8 + 3];
    #define FMA2(av, r) \
      acc[r].x = fmaf(av, w.x, acc[r].x); acc[r].y = fmaf(av, w.y, acc[r].y);
    FMA2(a0.x, 0)  FMA2(a0.y, 1)  FMA2(a0.z, 2)  FMA2(a0.w, 3)
    FMA2(a1.x, 4)  FMA2(a1.y, 5)  FMA2(a1.z, 6)  FMA2(a1.w, 7)
    FMA2(a2.x, 8)  FMA2(a2.y, 9)  FMA2(a2.z, 10) FMA2(a2.w, 11)
    FMA2(a3.x, 12) FMA2(a3.y, 13) FMA2(a3.z, 14) FMA2(a3.w, 15)
    #undef FMA2
  }

  float* o = P2 + (size_t)kid * 32 * 4096 + n;
  #pragma unroll
  for (int r = 0; r < 16; ++r) {
    int m = mh16 + r;
    *(float2*)(o + (size_t)m * 4096) = acc[r];
  }
}

// ---------------------------------------------------------------------------
// Kernel 5: reduce split-K partials of the output projection -> d_out.
// float4-vectorized: 32768 float4s, grid = 128 x 256.
// ---------------------------------------------------------------------------
__global__ __launch_bounds__(256) void oproj_reduce(
    const float* __restrict__ P2, float* __restrict__ out) {
  const int idx = blockIdx.x * 256 + threadIdx.x;  // float4 index
  const float4* p4 = (const float4*)P2;
  float4 s = {0.f, 0.f, 0.f, 0.f};
  #pragma unroll
  for (int t = 0; t < OKSPLIT_; ++t) {
    float4 v = p4[(size_t)t * 32768 + idx];
    s.x += v.x; s.y += v.y; s.z += v.z; s.w += v.w;
  }
  ((float4*)out)[idx] = s;
}

// ---------------------------------------------------------------------------
extern "C" void kernel_launch(void* const* d_in, const int* in_sizes, int n_in,
                              void* d_out, int out_size, void* d_ws, size_t ws_size,
                              hipStream_t stream) {
  const float* seqs = (const float*)d_in[0];
  const float* Wq   = (const float*)d_in[1];
  const float* Wk   = (const float*)d_in[2];
  const float* Wv   = (const float*)d_in[3];
  const float* Wo   = (const float*)d_in[4];
  const float* qn_w = (const float*)d_in[5];
  const float* kn_w = (const float*)d_in[6];
  const float* kc   = (const float*)d_in[7];
  const float* vc   = (const float*)d_in[8];
  const int* input_pos = (const int*)d_in[9];
  const int* slot_map  = (const int*)d_in[10];
  const int* btab      = (const int*)d_in[11];
  const int* ctx       = (const int*)d_in[12];
  float* out = (float*)d_out;

  char* w = (char*)d_ws;
  float* seqsT = (float*)(w);                    //      524,288
  float* P1    = (float*)(w + 524288);           //   25,165,824 (32 splits)
  float* qf    = (float*)(w + 25690112);         //      524,288
  float* knew  = (float*)(w + 26214400);         //      131,072
  float* vnew  = (float*)(w + 26345472);         //      131,072
  float* attnT = (float*)(w + 26476544);         //      524,288
  float* pacc  = (float*)(w + 27000832);         //    8,388,608 (16 splits)
  float* pls   = (float*)(w + 35389440);         //       65,536
  float* P2    = (float*)(w + 35454976);         //   16,777,216 (32 splits)

  transpose32<<<64, 256, 0, stream>>>(seqs, seqsT);
  qkv_gemm<<<24 * QKSPLIT_, 256, 0, stream>>>(seqsT, Wq, Wk, Wv, P1);
  reduce_norm_rope<<<B_ * 48, 128, 0, stream>>>(P1, qn_w, kn_w, input_pos, qf, knew, vnew);
  attn_decode<<<B_ * ASPLIT_, 512, 0, stream>>>(qf, knew, vnew, kc, vc, btab, slot_map, ctx, pacc, pls);
  attn_mergeT<<<128, 256, 0, stream>>>(pacc, pls, attnT);
  oproj_gemm<<<16 * OKSPLIT_, 256, 0, stream>>>(attnT, Wo, P2);
  oproj_reduce<<<128, 256, 0, stream>>>(P2, out);
}